// Round 7
// baseline (2257.169 us; speedup 1.0000x reference)
//
#include <hip/hip_runtime.h>

// ForexLSTM: 2-layer LSTM (B=1024, T=512, D=14, H=128) + batchnorm-over-batch + MLP(128->32->1)
//
// Round 6: layer-specialized wave groups (producer/consumer). Grid=256 -> 1 block/CU,
// so barriers drain the whole CU; R4/R5 showed ~70% stall. Fix: 1024 threads (16 waves),
// waves 0-7 compute ONLY layer-0, waves 8-15 ONLY layer-1, in separate loops with
// matched barrier counts (one __syncthreads per phase, 513 phases). Phase p: group A
// does L0(t=p) [needs h1(p-1), x(p)]; group B does L1(t=p-1) [needs h1(p-1), h2(p-2)].
// All inputs ready at phase start -> the two groups overlap structurally.
//   - Per-wave regs halve: A = Wih0(16)+Whh0(64); B = Wih1(64)+Whh1(64, all 4 kt in regs).
//     No whh1k3 LDS tile; LDS = 18 KB.
//   - Dataflow/fragments/activations verbatim from validated R4: weights as A-frags,
//     D[row=gate,col=batch], in-register act + c-state, h in B-frag LDS layout,
//     bias0 folded via x_aug[15]=1, bias1 in packed regs.

#define B_ 1024
#define T_ 512
#define D_ 14
#define H_ 128
#define NB 4
#define NT 1024

typedef _Float16 f16;
typedef _Float16 half4 __attribute__((ext_vector_type(4)));
typedef _Float16 half8 __attribute__((ext_vector_type(8)));
typedef _Float16 f16x2 __attribute__((ext_vector_type(2)));
typedef float floatx4 __attribute__((ext_vector_type(4)));

__device__ __forceinline__ float fexp(float x) {
    return __builtin_amdgcn_exp2f(x * 1.44269504088896f);
}
__device__ __forceinline__ float sigm(float x) {
    return __builtin_amdgcn_rcpf(1.0f + fexp(-x));
}
__device__ __forceinline__ float tanh_(float x) {
    return 1.0f - 2.0f * __builtin_amdgcn_rcpf(1.0f + fexp(2.0f * x));
}

__device__ __forceinline__ half8 ldfrag(const float* __restrict__ p) {
    half8 r;
#pragma unroll
    for (int j = 0; j < 8; ++j) r[j] = (f16)p[j];
    return r;
}

#define MFMA(a, b, c) __builtin_amdgcn_mfma_f32_16x16x32_f16((a), (b), (c), 0, 0, 0)

__global__ __launch_bounds__(NT, 4) void lstm_fused(
    const float* __restrict__ x,
    const float* __restrict__ Wih0, const float* __restrict__ Whh0,
    const float* __restrict__ bih0, const float* __restrict__ bhh0,
    const float* __restrict__ Wih1, const float* __restrict__ Whh1,
    const float* __restrict__ bih1, const float* __restrict__ bhh1,
    float* __restrict__ h2last)
{
    // LDS: 8 + 8 + 2 = 18 KB
    __shared__ __align__(16) f16 h1f[2][4][64][8];    // [buf][kt][lane][e] B-frag layout
    __shared__ __align__(16) f16 h2f[2][4][64][8];
    __shared__ __align__(16) f16 xf[2][64][8];        // x_aug B-frags (K=16: 14 x, 0, 1.0)

    const int tid = threadIdx.x;
    const int lane = tid & 63;
    const int wv = tid >> 6;          // wave 0..15
    const int n = lane & 15;          // batch column (valid < NB) / A-row index
    const int q = lane >> 4;          // quad -> D rows q*4+r
    const int b0 = blockIdx.x * NB;
    const int jg = (wv & 7) * 16;     // j-group base within the wave's layer
    // h write-back target: j = jg + q*4 + r -> kt, lane slot n+16*qw, elem eb+r
    const int ktw = (wv & 7) >> 1;
    const int qw = (wv & 1) * 2 + (q >> 1);
    const int eb = (q & 1) * 4;

    // ---- zero state buffers: h1f, h2f = 2048 dwords each; xf = 512 dwords ----
    {
        unsigned int* z1 = (unsigned int*)h1f;
        unsigned int* z2 = (unsigned int*)h2f;
        z1[tid] = 0u; z1[tid + 1024] = 0u;
        z2[tid] = 0u; z2[tid + 1024] = 0u;
        if (tid < 512) ((unsigned int*)xf)[tid] = 0u;
    }
    __syncthreads();

    // ---- x_aug constants (k==15 -> 1.0 in BOTH buffers) + stage x(0) into xf[0] ----
    if (tid < NB) {
        xf[0][tid + 16][7] = (f16)1.0f;
        xf[1][tid + 16][7] = (f16)1.0f;
    }
    if (tid < 64) {
        int nn = tid & 15, kq = tid >> 4;
        if (nn < NB && kq < 2) {
            half8 v;
#pragma unroll
            for (int e = 0; e < 8; ++e) {
                int k = kq * 8 + e;
                v[e] = (k < D_) ? (f16)x[(size_t)(b0 + nn) * T_ * D_ + k]
                                : (k == 15 ? (f16)1.0f : (f16)0.0f);
            }
            *(half8*)&xf[0][tid][0] = v;
        }
    }
    __syncthreads();

    if (wv < 8) {
        // ================= GROUP A: layer-0, phases p = 0..T (work if p < T) =========
        half8 aWhh0[4][4], aWih0[4];
#pragma unroll
        for (int ni = 0; ni < 4; ++ni) {
            const int g = ni * 128 + jg + n;
#pragma unroll
            for (int kt = 0; kt < 4; ++kt)
                aWhh0[ni][kt] = ldfrag(Whh0 + (size_t)g * H_ + kt * 32 + q * 8);
            half8 w0;
#pragma unroll
            for (int e = 0; e < 8; ++e) {
                int k = q * 8 + e;
                if (k < D_)       w0[e] = (f16)Wih0[(size_t)g * D_ + k];
                else if (k == 15) w0[e] = (f16)(bih0[g] + bhh0[g]);
                else              w0[e] = (f16)0.0f;
            }
            aWih0[ni] = w0;
        }

        floatx4 c1 = {0.f, 0.f, 0.f, 0.f};
        for (int p = 0; p <= T_; ++p) {
            const int cur = p & 1, nxt = cur ^ 1;
            if (p < T_) {
                // x(p+1) prefetch (threads 0..55 live in wave 0 = group A)
                float xp = 0.0f;
                if (tid < NB * D_ && (p + 1) < T_)
                    xp = x[(size_t)(b0 + (tid & 3)) * T_ * D_ + (size_t)(p + 1) * D_ + (tid >> 2)];

                floatx4 C0[4];
#pragma unroll
                for (int ni = 0; ni < 4; ++ni) C0[ni] = floatx4{0.f, 0.f, 0.f, 0.f};
                {
                    half8 bx = *(const half8*)&xf[cur][lane][0];
#pragma unroll
                    for (int ni = 0; ni < 4; ++ni) C0[ni] = MFMA(aWih0[ni], bx, C0[ni]);
                }
#pragma unroll
                for (int kt = 0; kt < 4; ++kt) {
                    half8 bh = *(const half8*)&h1f[cur][kt][lane][0];
#pragma unroll
                    for (int ni = 0; ni < 4; ++ni) C0[ni] = MFMA(aWhh0[ni][kt], bh, C0[ni]);
                }
                half4 hp;
#pragma unroll
                for (int r = 0; r < 4; ++r) {
                    float i_ = sigm(C0[0][r]);
                    float f_ = sigm(C0[1][r]);
                    float g_ = tanh_(C0[2][r]);
                    float o_ = sigm(C0[3][r]);
                    c1[r] = f_ * c1[r] + i_ * g_;
                    hp[r] = (f16)(o_ * tanh_(c1[r]));
                }
                if (n < NB) *(half4*)&h1f[nxt][ktw][n + 16 * qw][eb] = hp;
                // restage x(p+1) (k slots 0..13; 14/15 constant from init)
                if (tid < NB * D_ && (p + 1) < T_) {
                    int k = tid >> 2;
                    xf[nxt][(tid & 3) + 16 * (k >> 3)][k & 7] = (f16)xp;
                }
            }
            __syncthreads();
        }
    } else {
        // ================= GROUP B: layer-1, phases p = 0..T (work if p >= 1) ========
        half8 aWih1[4][4], aWhh1[4][4];
        f16x2 b1p[4][2];
#pragma unroll
        for (int ni = 0; ni < 4; ++ni) {
            const int g = ni * 128 + jg + n;
#pragma unroll
            for (int kt = 0; kt < 4; ++kt) {
                aWih1[ni][kt] = ldfrag(Wih1 + (size_t)g * H_ + kt * 32 + q * 8);
                aWhh1[ni][kt] = ldfrag(Whh1 + (size_t)g * H_ + kt * 32 + q * 8);
            }
            const int gb = ni * 128 + jg + q * 4;
            f16x2 p0, p1;
            p0[0] = (f16)(bih1[gb]     + bhh1[gb]);
            p0[1] = (f16)(bih1[gb + 1] + bhh1[gb + 1]);
            p1[0] = (f16)(bih1[gb + 2] + bhh1[gb + 2]);
            p1[1] = (f16)(bih1[gb + 3] + bhh1[gb + 3]);
            b1p[ni][0] = p0;
            b1p[ni][1] = p1;
        }

        floatx4 c2 = {0.f, 0.f, 0.f, 0.f};
        for (int p = 0; p <= T_; ++p) {
            const int cur = p & 1, nxt = cur ^ 1;
            if (p >= 1) {
                floatx4 C1[4];
#pragma unroll
                for (int ni = 0; ni < 4; ++ni) C1[ni] = floatx4{0.f, 0.f, 0.f, 0.f};
#pragma unroll
                for (int kt = 0; kt < 4; ++kt) {
                    half8 bh = *(const half8*)&h1f[cur][kt][lane][0];     // h1(p-1)
#pragma unroll
                    for (int ni = 0; ni < 4; ++ni) C1[ni] = MFMA(aWih1[ni][kt], bh, C1[ni]);
                }
#pragma unroll
                for (int kt = 0; kt < 4; ++kt) {
                    half8 bh = *(const half8*)&h2f[cur][kt][lane][0];     // h2(p-2)
#pragma unroll
                    for (int ni = 0; ni < 4; ++ni) C1[ni] = MFMA(aWhh1[ni][kt], bh, C1[ni]);
                }
                half4 hp;
                floatx4 hv;
#pragma unroll
                for (int r = 0; r < 4; ++r) {
                    float pi = C1[0][r] + (float)b1p[0][r >> 1][r & 1];
                    float pf = C1[1][r] + (float)b1p[1][r >> 1][r & 1];
                    float pg = C1[2][r] + (float)b1p[2][r >> 1][r & 1];
                    float po = C1[3][r] + (float)b1p[3][r >> 1][r & 1];
                    float i_ = sigm(pi), f_ = sigm(pf), g_ = tanh_(pg), o_ = sigm(po);
                    c2[r] = f_ * c2[r] + i_ * g_;
                    hv[r] = o_ * tanh_(c2[r]);
                    hp[r] = (f16)hv[r];
                }
                if (n < NB) {
                    *(half4*)&h2f[nxt][ktw][n + 16 * qw][eb] = hp;
                    if (p == T_) {
#pragma unroll
                        for (int r = 0; r < 4; ++r)
                            h2last[(size_t)(b0 + n) * H_ + jg + q * 4 + r] = hv[r];
                    }
                }
            }
            __syncthreads();
        }
    }
}

// batch-norm statistics over the batch dim: 1 block, 1024 threads
__global__ void bn_stats(const float* __restrict__ h2last, float* __restrict__ stats)
{
    __shared__ float red[2][8][128];
    const int tid = threadIdx.x;
    const int j = tid & 127, bs = tid >> 7;
    float s = 0.0f, ss = 0.0f;
    for (int bb = 0; bb < 128; ++bb) {
        float v = h2last[(size_t)(bb * 8 + bs) * H_ + j];
        s += v;
        ss += v * v;
    }
    red[0][bs][j] = s;
    red[1][bs][j] = ss;
    __syncthreads();
    if (tid < 128) {
        float S = 0.0f, SS = 0.0f;
#pragma unroll
        for (int k = 0; k < 8; ++k) { S += red[0][k][tid]; SS += red[1][k][tid]; }
        float mu = S * (1.0f / 1024.0f);
        float var = SS * (1.0f / 1024.0f) - mu * mu;
        stats[tid] = mu;
        stats[128 + tid] = __builtin_amdgcn_rsqf(var + 1e-5f);
    }
}

// normalize + MLP head: 8 blocks x 128 threads, one batch element per thread
__global__ void bn_mlp(const float* __restrict__ h2last, const float* __restrict__ stats,
                       const float* __restrict__ gamma, const float* __restrict__ beta,
                       const float* __restrict__ W1, const float* __restrict__ b1,
                       const float* __restrict__ W2, const float* __restrict__ b2,
                       float* __restrict__ out)
{
    __shared__ float W1T[128][33];
    __shared__ float mus[128], isds[128], gs[128], bts[128], w2s[32];
    const int tid = threadIdx.x;
    const int b = blockIdx.x * 128 + tid;

    for (int i = tid; i < 4096; i += 128) {
        int k = i >> 7, j = i & 127;
        W1T[j][k] = W1[i];
    }
    mus[tid] = stats[tid];
    isds[tid] = stats[128 + tid];
    gs[tid] = gamma[tid];
    bts[tid] = beta[tid];
    if (tid < 32) w2s[tid] = W2[tid];
    __syncthreads();

    float z[32];
#pragma unroll
    for (int k = 0; k < 32; ++k) z[k] = b1[k];

    for (int j = 0; j < 128; ++j) {
        float nv = (h2last[(size_t)b * H_ + j] - mus[j]) * isds[j] * gs[j] + bts[j];
#pragma unroll
        for (int k = 0; k < 32; ++k) z[k] += W1T[j][k] * nv;
    }
    float o = b2[0];
#pragma unroll
    for (int k = 0; k < 32; ++k) o += w2s[k] * fmaxf(z[k], 0.0f);
    out[b] = o;
}

extern "C" void kernel_launch(void* const* d_in, const int* in_sizes, int n_in,
                              void* d_out, int out_size, void* d_ws, size_t ws_size,
                              hipStream_t stream)
{
    const float* x    = (const float*)d_in[0];
    const float* Wih0 = (const float*)d_in[1];
    const float* Whh0 = (const float*)d_in[2];
    const float* bih0 = (const float*)d_in[3];
    const float* bhh0 = (const float*)d_in[4];
    const float* Wih1 = (const float*)d_in[5];
    const float* Whh1 = (const float*)d_in[6];
    const float* bih1 = (const float*)d_in[7];
    const float* bhh1 = (const float*)d_in[8];
    const float* gamma = (const float*)d_in[9];
    const float* beta  = (const float*)d_in[10];
    const float* W1 = (const float*)d_in[11];
    const float* b1 = (const float*)d_in[12];
    const float* W2 = (const float*)d_in[13];
    const float* b2 = (const float*)d_in[14];

    float* h2last = (float*)d_ws;              // 1024*128 floats = 512 KB
    float* stats  = h2last + (size_t)B_ * H_;  // 256 floats
    float* out = (float*)d_out;

    hipLaunchKernelGGL(lstm_fused, dim3(B_ / NB), dim3(NT), 0, stream,
                       x, Wih0, Whh0, bih0, bhh0, Wih1, Whh1, bih1, bhh1, h2last);
    hipLaunchKernelGGL(bn_stats, dim3(1), dim3(1024), 0, stream, h2last, stats);
    hipLaunchKernelGGL(bn_mlp, dim3(8), dim3(128), 0, stream,
                       h2last, stats, gamma, beta, W1, b1, W2, b2, out);
}

// Round 8
// 1156.166 us; speedup vs baseline: 1.9523x; 1.9523x over previous
//
#include <hip/hip_runtime.h>

// ForexLSTM: 2-layer LSTM (B=1024, T=512, D=14, H=128) + batchnorm-over-batch + MLP(128->32->1)
//
// Round 7: layer-specialized wave groups at the CORRECT register width.
// Lesson R5/R6: per-thread total reg budget (VGPR+AGPR unified) = 512 / waves-per-SIMD.
// 8 waves (512 thr) -> 256/thread (R4 proved ~230 fits); 16 waves -> 128 (spills).
// So: 512 threads, waves 0-3 compute ONLY layer-0 (2 j-groups each), waves 4-7 ONLY
// layer-1 (2 j-groups each), separate loops, ONE __syncthreads per phase (513 phases).
// Phase p: L0(t=p) needs {h1(p-1), x(p)}; L1(t=p-1) needs {h1(p-1), h2(p-2)} - all
// ready at phase start, double-buffered h1f/h2f.
//   - L0 wave regs: Whh0 2jgx4gx4kt=128 + Wih0 32 + C 32 + c1 8  ~ 220.
//   - L1 wave regs: Wih1 128 + Whh1-kt0 32 + C 32 + c2 8 + b1p 16 ~ 236.
//     Whh1 kt1-3 live in LDS (96 KB), lane-striped conflict-free b128 reads.
//   - All fragment layouts / activation math verbatim from validated R4.

#define B_ 1024
#define T_ 512
#define D_ 14
#define H_ 128
#define NB 4
#define NT 512

typedef _Float16 f16;
typedef _Float16 half4 __attribute__((ext_vector_type(4)));
typedef _Float16 half8 __attribute__((ext_vector_type(8)));
typedef _Float16 f16x2 __attribute__((ext_vector_type(2)));
typedef float floatx4 __attribute__((ext_vector_type(4)));

__device__ __forceinline__ float fexp(float x) {
    return __builtin_amdgcn_exp2f(x * 1.44269504088896f);
}
__device__ __forceinline__ float sigm(float x) {
    return __builtin_amdgcn_rcpf(1.0f + fexp(-x));
}
__device__ __forceinline__ float tanh_(float x) {
    return 1.0f - 2.0f * __builtin_amdgcn_rcpf(1.0f + fexp(2.0f * x));
}

__device__ __forceinline__ half8 ldfrag(const float* __restrict__ p) {
    half8 r;
#pragma unroll
    for (int j = 0; j < 8; ++j) r[j] = (f16)p[j];
    return r;
}

#define MFMA(a, b, c) __builtin_amdgcn_mfma_f32_16x16x32_f16((a), (b), (c), 0, 0, 0)

__global__ __launch_bounds__(NT, 2) void lstm_fused(
    const float* __restrict__ x,
    const float* __restrict__ Wih0, const float* __restrict__ Whh0,
    const float* __restrict__ bih0, const float* __restrict__ bhh0,
    const float* __restrict__ Wih1, const float* __restrict__ Whh1,
    const float* __restrict__ bih1, const float* __restrict__ bhh1,
    float* __restrict__ h2last)
{
    // LDS: 96 + 8 + 8 + 2 = 114 KB
    __shared__ __align__(16) f16 whh1lds[8][4][3][64][8];  // [wg][gate][kt-1][lane][e]
    __shared__ __align__(16) f16 h1f[2][4][64][8];         // [buf][kt][lane][e] B-frag
    __shared__ __align__(16) f16 h2f[2][4][64][8];
    __shared__ __align__(16) f16 xf[2][64][8];             // x_aug (K=16: 14 x, 0, 1.0)

    const int tid = threadIdx.x;
    const int lane = tid & 63;
    const int wv = tid >> 6;          // wave 0..7
    const int n = lane & 15;          // batch column (valid < NB) / A-row index
    const int q = lane >> 4;          // quad -> D rows q*4+r
    const int b0 = blockIdx.x * NB;

    // ---- zero state buffers: h1f,h2f = 4096 dwords total; xf = 512 dwords ----
    {
        unsigned int* z1 = (unsigned int*)h1f;
        unsigned int* z2 = (unsigned int*)h2f;
#pragma unroll
        for (int i = 0; i < 4; ++i) {
            z1[tid + i * 512] = 0u;
            z2[tid + i * 512] = 0u;
        }
        ((unsigned int*)xf)[tid] = 0u;
    }
    __syncthreads();

    // ---- x_aug constants (k==15 -> 1.0 in BOTH buffers) + stage x(0) into xf[0] ----
    if (tid < NB) {
        xf[0][tid + 16][7] = (f16)1.0f;
        xf[1][tid + 16][7] = (f16)1.0f;
    }
    if (tid < 64) {
        int nn = tid & 15, kq = tid >> 4;
        if (nn < NB && kq < 2) {
            half8 v;
#pragma unroll
            for (int e = 0; e < 8; ++e) {
                int k = kq * 8 + e;
                v[e] = (k < D_) ? (f16)x[(size_t)(b0 + nn) * T_ * D_ + k]
                                : (k == 15 ? (f16)1.0f : (f16)0.0f);
            }
            *(half8*)&xf[0][tid][0] = v;
        }
    }

    if (wv < 4) {
        // ================= GROUP A: layer-0, waves 0-3, j-groups {2wv, 2wv+1} ========
        half8 aWhh0[2][4][4], aWih0[2][4];
#pragma unroll
        for (int jj = 0; jj < 2; ++jj) {
            const int wg = 2 * wv + jj;
#pragma unroll
            for (int g = 0; g < 4; ++g) {
                const int gr = g * 128 + wg * 16 + n;
#pragma unroll
                for (int kt = 0; kt < 4; ++kt)
                    aWhh0[jj][g][kt] = ldfrag(Whh0 + (size_t)gr * H_ + kt * 32 + q * 8);
                half8 w0;
#pragma unroll
                for (int e = 0; e < 8; ++e) {
                    int k = q * 8 + e;
                    if (k < D_)       w0[e] = (f16)Wih0[(size_t)gr * D_ + k];
                    else if (k == 15) w0[e] = (f16)(bih0[gr] + bhh0[gr]);
                    else              w0[e] = (f16)0.0f;
                }
                aWih0[jj][g] = w0;
            }
        }
        floatx4 c1[2] = {{0.f, 0.f, 0.f, 0.f}, {0.f, 0.f, 0.f, 0.f}};
        __syncthreads();

        for (int p = 0; p <= T_; ++p) {
            const int cur = p & 1, nxt = cur ^ 1;
            if (p < T_) {
                float xp = 0.0f;
                if (tid < NB * D_ && (p + 1) < T_)
                    xp = x[(size_t)(b0 + (tid & 3)) * T_ * D_ + (size_t)(p + 1) * D_ + (tid >> 2)];

                floatx4 C0[2][4];
#pragma unroll
                for (int jj = 0; jj < 2; ++jj)
#pragma unroll
                    for (int g = 0; g < 4; ++g) C0[jj][g] = floatx4{0.f, 0.f, 0.f, 0.f};
                {
                    half8 bx = *(const half8*)&xf[cur][lane][0];
#pragma unroll
                    for (int jj = 0; jj < 2; ++jj)
#pragma unroll
                        for (int g = 0; g < 4; ++g) C0[jj][g] = MFMA(aWih0[jj][g], bx, C0[jj][g]);
                }
#pragma unroll
                for (int kt = 0; kt < 4; ++kt) {
                    half8 bh = *(const half8*)&h1f[cur][kt][lane][0];
#pragma unroll
                    for (int jj = 0; jj < 2; ++jj)
#pragma unroll
                        for (int g = 0; g < 4; ++g) C0[jj][g] = MFMA(aWhh0[jj][g][kt], bh, C0[jj][g]);
                }
#pragma unroll
                for (int jj = 0; jj < 2; ++jj) {
                    half4 hp;
#pragma unroll
                    for (int r = 0; r < 4; ++r) {
                        float i_ = sigm(C0[jj][0][r]);
                        float f_ = sigm(C0[jj][1][r]);
                        float g_ = tanh_(C0[jj][2][r]);
                        float o_ = sigm(C0[jj][3][r]);
                        c1[jj][r] = f_ * c1[jj][r] + i_ * g_;
                        hp[r] = (f16)(o_ * tanh_(c1[jj][r]));
                    }
                    const int wg = 2 * wv + jj;
                    const int ktw = wg >> 1;
                    const int qw = (wg & 1) * 2 + (q >> 1);
                    const int eb = (q & 1) * 4;
                    if (n < NB) *(half4*)&h1f[nxt][ktw][n + 16 * qw][eb] = hp;
                }
                if (tid < NB * D_ && (p + 1) < T_) {
                    int k = tid >> 2;
                    xf[nxt][(tid & 3) + 16 * (k >> 3)][k & 7] = (f16)xp;
                }
            }
            __syncthreads();
        }
    } else {
        // ================= GROUP B: layer-1, waves 4-7, j-groups {2w, 2w+1} ==========
        const int w = wv - 4;
        half8 aWih1[2][4][4], aWhh1k0[2][4];
        f16x2 b1p[2][4][2];
#pragma unroll
        for (int jj = 0; jj < 2; ++jj) {
            const int wg = 2 * w + jj;
#pragma unroll
            for (int g = 0; g < 4; ++g) {
                const int gr = g * 128 + wg * 16 + n;
#pragma unroll
                for (int kt = 0; kt < 4; ++kt) {
                    aWih1[jj][g][kt] = ldfrag(Wih1 + (size_t)gr * H_ + kt * 32 + q * 8);
                    half8 wf = ldfrag(Whh1 + (size_t)gr * H_ + kt * 32 + q * 8);
                    if (kt == 0) aWhh1k0[jj][g] = wf;
                    else         *(half8*)&whh1lds[wg][g][kt - 1][lane][0] = wf;
                }
                const int gb = g * 128 + wg * 16 + q * 4;
                f16x2 p0, p1;
                p0[0] = (f16)(bih1[gb]     + bhh1[gb]);
                p0[1] = (f16)(bih1[gb + 1] + bhh1[gb + 1]);
                p1[0] = (f16)(bih1[gb + 2] + bhh1[gb + 2]);
                p1[1] = (f16)(bih1[gb + 3] + bhh1[gb + 3]);
                b1p[jj][g][0] = p0;
                b1p[jj][g][1] = p1;
            }
        }
        floatx4 c2[2] = {{0.f, 0.f, 0.f, 0.f}, {0.f, 0.f, 0.f, 0.f}};
        __syncthreads();

        for (int p = 0; p <= T_; ++p) {
            const int cur = p & 1, nxt = cur ^ 1;
            if (p >= 1) {
                floatx4 C1[2][4];
#pragma unroll
                for (int jj = 0; jj < 2; ++jj)
#pragma unroll
                    for (int g = 0; g < 4; ++g) C1[jj][g] = floatx4{0.f, 0.f, 0.f, 0.f};
#pragma unroll
                for (int kt = 0; kt < 4; ++kt) {
                    half8 bh = *(const half8*)&h1f[cur][kt][lane][0];     // h1(p-1)
#pragma unroll
                    for (int jj = 0; jj < 2; ++jj)
#pragma unroll
                        for (int g = 0; g < 4; ++g) C1[jj][g] = MFMA(aWih1[jj][g][kt], bh, C1[jj][g]);
                }
                {
                    half8 bh = *(const half8*)&h2f[cur][0][lane][0];      // h2(p-2), kt0
#pragma unroll
                    for (int jj = 0; jj < 2; ++jj)
#pragma unroll
                        for (int g = 0; g < 4; ++g) C1[jj][g] = MFMA(aWhh1k0[jj][g], bh, C1[jj][g]);
                }
#pragma unroll
                for (int kt = 1; kt < 4; ++kt) {
                    half8 bh = *(const half8*)&h2f[cur][kt][lane][0];     // h2(p-2), kt1-3
#pragma unroll
                    for (int jj = 0; jj < 2; ++jj) {
                        const int wg = 2 * w + jj;
#pragma unroll
                        for (int g = 0; g < 4; ++g) {
                            half8 aw = *(const half8*)&whh1lds[wg][g][kt - 1][lane][0];
                            C1[jj][g] = MFMA(aw, bh, C1[jj][g]);
                        }
                    }
                }
#pragma unroll
                for (int jj = 0; jj < 2; ++jj) {
                    half4 hp;
                    floatx4 hv;
#pragma unroll
                    for (int r = 0; r < 4; ++r) {
                        float pi = C1[jj][0][r] + (float)b1p[jj][0][r >> 1][r & 1];
                        float pf = C1[jj][1][r] + (float)b1p[jj][1][r >> 1][r & 1];
                        float pg = C1[jj][2][r] + (float)b1p[jj][2][r >> 1][r & 1];
                        float po = C1[jj][3][r] + (float)b1p[jj][3][r >> 1][r & 1];
                        float i_ = sigm(pi), f_ = sigm(pf), g_ = tanh_(pg), o_ = sigm(po);
                        c2[jj][r] = f_ * c2[jj][r] + i_ * g_;
                        hv[r] = o_ * tanh_(c2[jj][r]);
                        hp[r] = (f16)hv[r];
                    }
                    const int wg = 2 * w + jj;
                    const int ktw = wg >> 1;
                    const int qw = (wg & 1) * 2 + (q >> 1);
                    const int eb = (q & 1) * 4;
                    if (n < NB) {
                        *(half4*)&h2f[nxt][ktw][n + 16 * qw][eb] = hp;
                        if (p == T_) {
#pragma unroll
                            for (int r = 0; r < 4; ++r)
                                h2last[(size_t)(b0 + n) * H_ + wg * 16 + q * 4 + r] = hv[r];
                        }
                    }
                }
            }
            __syncthreads();
        }
    }
}

// batch-norm statistics over the batch dim: 1 block, 1024 threads
__global__ void bn_stats(const float* __restrict__ h2last, float* __restrict__ stats)
{
    __shared__ float red[2][8][128];
    const int tid = threadIdx.x;
    const int j = tid & 127, bs = tid >> 7;
    float s = 0.0f, ss = 0.0f;
    for (int bb = 0; bb < 128; ++bb) {
        float v = h2last[(size_t)(bb * 8 + bs) * H_ + j];
        s += v;
        ss += v * v;
    }
    red[0][bs][j] = s;
    red[1][bs][j] = ss;
    __syncthreads();
    if (tid < 128) {
        float S = 0.0f, SS = 0.0f;
#pragma unroll
        for (int k = 0; k < 8; ++k) { S += red[0][k][tid]; SS += red[1][k][tid]; }
        float mu = S * (1.0f / 1024.0f);
        float var = SS * (1.0f / 1024.0f) - mu * mu;
        stats[tid] = mu;
        stats[128 + tid] = __builtin_amdgcn_rsqf(var + 1e-5f);
    }
}

// normalize + MLP head: 8 blocks x 128 threads, one batch element per thread
__global__ void bn_mlp(const float* __restrict__ h2last, const float* __restrict__ stats,
                       const float* __restrict__ gamma, const float* __restrict__ beta,
                       const float* __restrict__ W1, const float* __restrict__ b1,
                       const float* __restrict__ W2, const float* __restrict__ b2,
                       float* __restrict__ out)
{
    __shared__ float W1T[128][33];
    __shared__ float mus[128], isds[128], gs[128], bts[128], w2s[32];
    const int tid = threadIdx.x;
    const int b = blockIdx.x * 128 + tid;

    for (int i = tid; i < 4096; i += 128) {
        int k = i >> 7, j = i & 127;
        W1T[j][k] = W1[i];
    }
    mus[tid] = stats[tid];
    isds[tid] = stats[128 + tid];
    gs[tid] = gamma[tid];
    bts[tid] = beta[tid];
    if (tid < 32) w2s[tid] = W2[tid];
    __syncthreads();

    float z[32];
#pragma unroll
    for (int k = 0; k < 32; ++k) z[k] = b1[k];

    for (int j = 0; j < 128; ++j) {
        float nv = (h2last[(size_t)b * H_ + j] - mus[j]) * isds[j] * gs[j] + bts[j];
#pragma unroll
        for (int k = 0; k < 32; ++k) z[k] += W1T[j][k] * nv;
    }
    float o = b2[0];
#pragma unroll
    for (int k = 0; k < 32; ++k) o += w2s[k] * fmaxf(z[k], 0.0f);
    out[b] = o;
}

extern "C" void kernel_launch(void* const* d_in, const int* in_sizes, int n_in,
                              void* d_out, int out_size, void* d_ws, size_t ws_size,
                              hipStream_t stream)
{
    const float* x    = (const float*)d_in[0];
    const float* Wih0 = (const float*)d_in[1];
    const float* Whh0 = (const float*)d_in[2];
    const float* bih0 = (const float*)d_in[3];
    const float* bhh0 = (const float*)d_in[4];
    const float* Wih1 = (const float*)d_in[5];
    const float* Whh1 = (const float*)d_in[6];
    const float* bih1 = (const float*)d_in[7];
    const float* bhh1 = (const float*)d_in[8];
    const float* gamma = (const float*)d_in[9];
    const float* beta  = (const float*)d_in[10];
    const float* W1 = (const float*)d_in[11];
    const float* b1 = (const float*)d_in[12];
    const float* W2 = (const float*)d_in[13];
    const float* b2 = (const float*)d_in[14];

    float* h2last = (float*)d_ws;              // 1024*128 floats = 512 KB
    float* stats  = h2last + (size_t)B_ * H_;  // 256 floats
    float* out = (float*)d_out;

    hipLaunchKernelGGL(lstm_fused, dim3(B_ / NB), dim3(NT), 0, stream,
                       x, Wih0, Whh0, bih0, bhh0, Wih1, Whh1, bih1, bhh1, h2last);
    hipLaunchKernelGGL(bn_stats, dim3(1), dim3(1024), 0, stream, h2last, stats);
    hipLaunchKernelGGL(bn_mlp, dim3(8), dim3(128), 0, stream,
                       h2last, stats, gamma, beta, W1, b1, W2, b2, out);
}